// Round 9
// baseline (299.135 us; speedup 1.0000x reference)
//
#include <hip/hip_runtime.h>

#define N_NODES 25000
#define N_EDGES 400000
#define IN_CH 1024
#define FC 128
#define ADD_CH 20
#define XCH 148   // FC + ADD
#define MID 37
#define OUT_CH 3
#define MAXDEG 64

typedef short bf16x8 __attribute__((ext_vector_type(8)));
typedef float f32x4 __attribute__((ext_vector_type(4)));

__device__ __forceinline__ unsigned int f2bf(float x) {
    unsigned int u = __builtin_bit_cast(unsigned int, x);
    unsigned int lsb = (u >> 16) & 1u;
    u += 0x7fffu + lsb;           // round-to-nearest-even
    return u >> 16;
}
__device__ __forceinline__ unsigned int pkbf(float a, float b) {
    return f2bf(a) | (f2bf(b) << 16);
}
__device__ __forceinline__ float bflo(unsigned int v) {
    return __builtin_bit_cast(float, v << 16);
}
__device__ __forceinline__ float bfhi(unsigned int v) {
    return __builtin_bit_cast(float, v & 0xffff0000u);
}

// ---------------- hetero prep: W swizzle + CSR bucket build ----------------
// W frag layout: unit (chgrp, kt) = 64 lanes x 16 B contiguous; lane (q,l15)
// holds W[chgrp*16+l15][kt*32+q*8 .. +8] as bf16x8 -> wave frag load is one
// coalesced 1 KB global_load_dwordx4.
#define WSWZ_B 16
#define BUILD_B 1563

__global__ __launch_bounds__(256) void prep_kernel(const float* __restrict__ Wl,
                                                   const float* __restrict__ Wr,
                                                   const int* __restrict__ edges,
                                                   ushort* __restrict__ Wpk,
                                                   int* __restrict__ cursor,
                                                   int* __restrict__ col) {
    int b = blockIdx.x, t = threadIdx.x;
    if (b < WSWZ_B) {
        int w = t >> 6, lane = t & 63, l15 = lane & 15, q8 = (lane >> 4) * 8;
        int ch = b * 16 + l15;
        const float* src = (ch < FC) ? (Wl + (size_t)ch * IN_CH)
                                     : (Wr + (size_t)(ch - FC) * IN_CH);
        #pragma unroll
        for (int j = 0; j < 8; ++j) {
            int kt = w * 8 + j;
            float4 lo = *(const float4*)(src + kt * 32 + q8);
            float4 hi = *(const float4*)(src + kt * 32 + q8 + 4);
            uint4 pk;
            pk.x = pkbf(lo.x, lo.y); pk.y = pkbf(lo.z, lo.w);
            pk.z = pkbf(hi.x, hi.y); pk.w = pkbf(hi.z, hi.w);
            ((uint4*)Wpk)[(size_t)(b * 32 + kt) * 64 + lane] = pk;
        }
    } else {
        int e = (b - WSWZ_B) * 256 + t;
        if (e < N_EDGES) {
            int dst = edges[N_EDGES + e];
            int pos = atomicAdd(&cursor[dst], 1);
            if (pos < MAXDEG) col[dst * MAXDEG + pos] = edges[e];
        }
    }
}

// ---------------- fused stage + GEMM ----------------
// 782 blocks x 256 thr. Stage: 32 feature rows read coalesced (256 B runs),
// packed to bf16, written to LDS in frag layout; ONE __syncthreads total.
// K-loop: W frags from global (L2-hot 512 KB, depth-2 reg pipeline) +
// F frags via ds_read_b128 + 8 MFMA per kt. No per-K-tile barrier.
__global__ __launch_bounds__(256) void gemm_kernel(const float* __restrict__ A,
                                                   const ushort* __restrict__ Wpk,
                                                   ushort* __restrict__ Py,
                                                   ushort* __restrict__ Pz) {
    __shared__ __align__(16) ushort Fs[2 * 32 * 64 * 8];   // 64 KB frag layout
    int t = threadIdx.x, w = t >> 6, lane = t & 63;
    int l15 = lane & 15, q = lane >> 4;
    int m0 = blockIdx.x * 32;

    // W depth-2 pipeline preload (independent of LDS -> overlaps staging)
    const bf16x8* Wf = (const bf16x8*)Wpk + (size_t)(w * 4) * 32 * 64 + lane;
    bf16x8 aw[4], an[4];
    #pragma unroll
    for (int cf = 0; cf < 4; ++cf) aw[cf] = Wf[(size_t)cf * 32 * 64];

    // stage features -> LDS frags
    {
        int r = t >> 3;            // row-in-tile 0..31
        int p0 = t & 7;            // position 0..7
        int row = m0 + r; if (row >= N_NODES) row = N_NODES - 1;
        const float* src = A + (size_t)row * IN_CH;
        int g = r >> 4, l = r & 15;
        #pragma unroll
        for (int m = 0; m < 16; ++m) {
            int o = m * 8 + p0;        // octet 0..127 (8 floats each)
            int kt = o >> 2, qq = o & 3;
            float4 lo = *(const float4*)(src + o * 8);
            float4 hi = *(const float4*)(src + o * 8 + 4);
            uint4 pk;
            pk.x = pkbf(lo.x, lo.y); pk.y = pkbf(lo.z, lo.w);
            pk.z = pkbf(hi.x, hi.y); pk.w = pkbf(hi.z, hi.w);
            *(uint4*)&Fs[(size_t)((g * 32 + kt) * 64 + qq * 16 + l) * 8] = pk;
        }
    }
    __syncthreads();

    const bf16x8* Ff = (const bf16x8*)Fs + lane;
    f32x4 acc[4][2] = {};
    for (int kt = 0; kt < 32; ++kt) {
        if (kt + 1 < 32) {
            #pragma unroll
            for (int cf = 0; cf < 4; ++cf) an[cf] = Wf[(size_t)(cf * 32 + kt + 1) * 64];
        }
        bf16x8 b0 = Ff[(size_t)(0 * 32 + kt) * 64];
        bf16x8 b1 = Ff[(size_t)(1 * 32 + kt) * 64];
        #pragma unroll
        for (int cf = 0; cf < 4; ++cf) {
            acc[cf][0] = __builtin_amdgcn_mfma_f32_16x16x32_bf16(aw[cf], b0, acc[cf][0], 0, 0, 0);
            acc[cf][1] = __builtin_amdgcn_mfma_f32_16x16x32_bf16(aw[cf], b1, acc[cf][1], 0, 0, 0);
        }
        #pragma unroll
        for (int cf = 0; cf < 4; ++cf) aw[cf] = an[cf];
    }
    // D layout: ch = w*64 + cf*16 + q*4 + reg, node = m0 + g*16 + l15
    #pragma unroll
    for (int g = 0; g < 2; ++g) {
        int node = m0 + g * 16 + l15;
        if (node < N_NODES) {
            ushort* base = (w < 2) ? (Py + (size_t)node * FC + w * 64)
                                   : (Pz + (size_t)node * FC + (w - 2) * 64);
            #pragma unroll
            for (int cf = 0; cf < 4; ++cf) {
                f32x4 v = acc[cf][g];
                uint2 pk;
                pk.x = pkbf(v[0], v[1]);
                pk.y = pkbf(v[2], v[3]);
                *(uint2*)(base + cf * 16 + q * 4) = pk;
            }
        }
    }
}

// ---------------- fused gather + SAGE combine + MLP tail ----------------
// 256 thr = 4 waves = 4 nodes/block. Gather: 4 edges per dwordx4 (16 lanes x
// 16 B = one 256 B Py row), 4 rows in flight per group -> 16 edges per iter.
__global__ __launch_bounds__(256) void fused_tail(const ushort* __restrict__ Py,
                                                  const ushort* __restrict__ Pz,
                                                  const int* __restrict__ deg,
                                                  const int* __restrict__ col,
                                                  const float* __restrict__ addf,
                                                  const float* __restrict__ bl,
                                                  const float* __restrict__ W1,
                                                  const float* __restrict__ b1,
                                                  const float* __restrict__ W2,
                                                  const float* __restrict__ b2,
                                                  const float* __restrict__ gamma,
                                                  const float* __restrict__ beta,
                                                  const float* __restrict__ rmean,
                                                  const float* __restrict__ rvar,
                                                  float* __restrict__ out) {
    __shared__ float W1s[XCH][MID + 3];
    __shared__ float xbuf[4][XCH + 4];
    __shared__ float hbuf[4][MID + 3];
    int t = threadIdx.x;
    for (int idx = t; idx < MID * XCH; idx += 256) {
        int j = idx / XCH, k = idx - j * XCH;
        W1s[k][j] = W1[idx];
    }
    __syncthreads();
    int w = t >> 6, lane = t & 63;
    int n = blockIdx.x * 4 + w;
    bool valid = (n < N_NODES);
    int d = valid ? deg[n] : 0;
    if (d > MAXDEG) d = MAXDEG;
    int g = lane >> 4, c16 = lane & 15;
    float s[8] = {0.f, 0.f, 0.f, 0.f, 0.f, 0.f, 0.f, 0.f};
    if (d > 0) {
        int cidx = col[n * MAXDEG + (lane < d ? lane : 0)];
        for (int i = 0; i < d; i += 16) {
            int e[4];
            uint4 v[4];
            #pragma unroll
            for (int j = 0; j < 4; ++j) {
                int ee = i + g + j * 4;
                e[j] = __shfl(cidx, (ee < d) ? ee : 0);
            }
            #pragma unroll
            for (int j = 0; j < 4; ++j)
                v[j] = *(const uint4*)&Py[(size_t)e[j] * FC + c16 * 8];
            #pragma unroll
            for (int j = 0; j < 4; ++j) {
                if (i + g + j * 4 < d) {
                    s[0] += bflo(v[j].x); s[1] += bfhi(v[j].x);
                    s[2] += bflo(v[j].y); s[3] += bfhi(v[j].y);
                    s[4] += bflo(v[j].z); s[5] += bfhi(v[j].z);
                    s[6] += bflo(v[j].w); s[7] += bfhi(v[j].w);
                }
            }
        }
        #pragma unroll
        for (int r = 0; r < 8; ++r) {
            s[r] += __shfl_xor(s[r], 16);
            s[r] += __shfl_xor(s[r], 32);
        }
    }
    if (valid) {
        if (lane < 16) {
            #pragma unroll
            for (int r = 0; r < 8; ++r) xbuf[w][lane * 8 + r] = s[r];
        }
        float invd = 1.0f / (float)(d > 1 ? d : 1);
        unsigned int vr = *(const unsigned int*)&Pz[(size_t)n * FC + lane * 2];
        float x0 = xbuf[w][2 * lane] * invd + bl[2 * lane] + bflo(vr);
        float x1 = xbuf[w][2 * lane + 1] * invd + bl[2 * lane + 1] + bfhi(vr);
        x0 = (x0 >= 0.f) ? x0 : 0.01f * x0;
        x1 = (x1 >= 0.f) ? x1 : 0.01f * x1;
        xbuf[w][2 * lane] = x0;
        xbuf[w][2 * lane + 1] = x1;
        if (lane < ADD_CH) xbuf[w][FC + lane] = addf[(size_t)n * ADD_CH + lane];
        if (lane < MID) {
            float h = b1[lane];
            #pragma unroll 4
            for (int k = 0; k < XCH; ++k) h += W1s[k][lane] * xbuf[w][k];
            h = fmaxf(h, 0.0f);
            h = gamma[lane] * (h - rmean[lane]) * rsqrtf(rvar[lane] + 1e-5f) + beta[lane];
            hbuf[w][lane] = h;
        }
        if (lane < OUT_CH) {
            float o = b2[lane];
            #pragma unroll
            for (int j = 0; j < MID; ++j) o += W2[lane * MID + j] * hbuf[w][j];
            out[(size_t)n * OUT_CH + lane] = o;
        }
    }
}

// ---------------- launch ----------------

extern "C" void kernel_launch(void* const* d_in, const int* in_sizes, int n_in,
                              void* d_out, int out_size, void* d_ws, size_t ws_size,
                              hipStream_t stream) {
    const float* features = (const float*)d_in[0];
    const int*   edges    = (const int*)d_in[1];
    const float* addf     = (const float*)d_in[4];
    const float* Wl       = (const float*)d_in[5];
    const float* bl       = (const float*)d_in[6];
    const float* Wr       = (const float*)d_in[7];
    const float* W1       = (const float*)d_in[8];
    const float* b1       = (const float*)d_in[9];
    const float* W2       = (const float*)d_in[10];
    const float* b2       = (const float*)d_in[11];
    const float* gamma    = (const float*)d_in[12];
    const float* beta     = (const float*)d_in[13];
    const float* rmean    = (const float*)d_in[14];
    const float* rvar     = (const float*)d_in[15];
    float* out = (float*)d_out;

    char* ws = (char*)d_ws;
    size_t off = 0;
    ushort* Py = (ushort*)(ws + off);     off += (size_t)N_NODES * FC * 2;        // 6.4 MB
    ushort* Pz = (ushort*)(ws + off);     off += (size_t)N_NODES * FC * 2;        // 6.4 MB
    ushort* Wpk = (ushort*)(ws + off);    off += (size_t)16 * 32 * 64 * 16;       // 512 KB
    int* cursor = (int*)(ws + off);       off += (size_t)N_NODES * 4;             // 100 KB
    int* col = (int*)(ws + off);          off += (size_t)N_NODES * MAXDEG * 4;    // 6.4 MB

    (void)hipMemsetAsync(cursor, 0, (size_t)N_NODES * 4, stream);

    prep_kernel<<<WSWZ_B + BUILD_B, 256, 0, stream>>>(Wl, Wr, edges, Wpk, cursor, col);

    gemm_kernel<<<(N_NODES + 31) / 32, 256, 0, stream>>>(features, Wpk, Py, Pz);

    fused_tail<<<(N_NODES + 3) / 4, 256, 0, stream>>>(Py, Pz, cursor, col, addf, bl,
                                                      W1, b1, W2, b2, gamma, beta,
                                                      rmean, rvar, out);
}

// Round 10
// 295.066 us; speedup vs baseline: 1.0138x; 1.0138x over previous
//
#include <hip/hip_runtime.h>

#define N_NODES 25000
#define N_EDGES 400000
#define IN_CH 1024
#define FC 128
#define ADD_CH 20
#define XCH 148   // FC + ADD
#define MID 37
#define OUT_CH 3
#define MAXDEG 64

typedef short bf16x8 __attribute__((ext_vector_type(8)));
typedef float f32x4 __attribute__((ext_vector_type(4)));

__device__ __forceinline__ unsigned int f2bf(float x) {
    unsigned int u = __builtin_bit_cast(unsigned int, x);
    unsigned int lsb = (u >> 16) & 1u;
    u += 0x7fffu + lsb;           // round-to-nearest-even
    return u >> 16;
}
__device__ __forceinline__ unsigned int pkbf(float a, float b) {
    return f2bf(a) | (f2bf(b) << 16);
}
__device__ __forceinline__ float bflo(unsigned int v) {
    return __builtin_bit_cast(float, v << 16);
}
__device__ __forceinline__ float bfhi(unsigned int v) {
    return __builtin_bit_cast(float, v & 0xffff0000u);
}

// ---------------- hetero prep: W swizzle + CSR bucket build ----------------
// W frag layout: unit (chgrp, kt) = 64 lanes x 16 B contiguous; lane (q,l15)
// holds W[chgrp*16+l15][kt*32+q*8 .. +8] as bf16x8.
#define WSWZ_B 16
#define BUILD_B 1563

__global__ __launch_bounds__(256) void prep_kernel(const float* __restrict__ Wl,
                                                   const float* __restrict__ Wr,
                                                   const int* __restrict__ edges,
                                                   ushort* __restrict__ Wpk,
                                                   int* __restrict__ cursor,
                                                   int* __restrict__ col) {
    int b = blockIdx.x, t = threadIdx.x;
    if (b < WSWZ_B) {
        int w = t >> 6, lane = t & 63, l15 = lane & 15, q8 = (lane >> 4) * 8;
        int ch = b * 16 + l15;
        const float* src = (ch < FC) ? (Wl + (size_t)ch * IN_CH)
                                     : (Wr + (size_t)(ch - FC) * IN_CH);
        #pragma unroll
        for (int j = 0; j < 8; ++j) {
            int kt = w * 8 + j;
            float4 lo = *(const float4*)(src + kt * 32 + q8);
            float4 hi = *(const float4*)(src + kt * 32 + q8 + 4);
            uint4 pk;
            pk.x = pkbf(lo.x, lo.y); pk.y = pkbf(lo.z, lo.w);
            pk.z = pkbf(hi.x, hi.y); pk.w = pkbf(hi.z, hi.w);
            ((uint4*)Wpk)[(size_t)(b * 32 + kt) * 64 + lane] = pk;
        }
    } else {
        int e = (b - WSWZ_B) * 256 + t;
        if (e < N_EDGES) {
            int dst = edges[N_EDGES + e];
            int pos = atomicAdd(&cursor[dst], 1);
            if (pos < MAXDEG) col[dst * MAXDEG + pos] = edges[e];
        }
    }
}

// ---------------- fused stage + GEMM ----------------
// 782 blocks x 256 thr, one __syncthreads total.
// Staging: loads hoisted 16-deep per half-pass (launch_bounds(256,2) gives VGPR
// room); LDS index XOR-swizzled (l + qq rotation) to kill 8-way write conflicts
// (read side becomes 2-way = free). K-loop: W global frags depth-4 pipeline
// (8 KB in flight vs ~225cyc L2 latency) + ds_read frags + 8 MFMA per kt.
__global__ __launch_bounds__(256, 2) void gemm_kernel(const float* __restrict__ A,
                                                      const ushort* __restrict__ Wpk,
                                                      ushort* __restrict__ Py,
                                                      ushort* __restrict__ Pz) {
    __shared__ __align__(16) ushort Fs[2 * 32 * 64 * 8];   // 64 KB frag layout
    int t = threadIdx.x, w = t >> 6, lane = t & 63;
    int l15 = lane & 15, q = lane >> 4;
    int m0 = blockIdx.x * 32;

    const bf16x8* Wf = (const bf16x8*)Wpk + (size_t)(w * 4) * 32 * 64 + lane;

    // ---- stage features -> LDS frags (swizzled) ----
    {
        int r = t >> 3;            // row-in-tile 0..31
        int p0 = t & 7;            // position 0..7
        int row = m0 + r; if (row >= N_NODES) row = N_NODES - 1;
        const float* src = A + (size_t)row * IN_CH;
        int g = r >> 4, l = r & 15;
        #pragma unroll
        for (int h = 0; h < 2; ++h) {
            float4 lo[8], hi[8];
            #pragma unroll
            for (int m = 0; m < 8; ++m) {
                int o = (h * 8 + m) * 8 + p0;
                lo[m] = *(const float4*)(src + o * 8);
                hi[m] = *(const float4*)(src + o * 8 + 4);
            }
            #pragma unroll
            for (int m = 0; m < 8; ++m) {
                int o = (h * 8 + m) * 8 + p0;
                int kt = o >> 2, qq = o & 3;
                uint4 pk;
                pk.x = pkbf(lo[m].x, lo[m].y); pk.y = pkbf(lo[m].z, lo[m].w);
                pk.z = pkbf(hi[m].x, hi[m].y); pk.w = pkbf(hi[m].z, hi[m].w);
                int u = (g * 32 + kt) * 64 + qq * 16 + ((l + qq) & 15);
                *(uint4*)&Fs[(size_t)u * 8] = pk;
            }
        }
    }
    __syncthreads();

    // swizzled read offsets (within kt-block: unit = q*16 + (l15+q)&15)
    int ru = q * 16 + ((l15 + q) & 15);
    const bf16x8* F0 = (const bf16x8*)Fs + (0 * 32) * 64 + ru;
    const bf16x8* F1 = (const bf16x8*)Fs + (1 * 32) * 64 + ru;

    f32x4 acc[4][2] = {};
    bf16x8 aw[2][4], an[2][4], bw[2][2], bn[2][2];
    #pragma unroll
    for (int cf = 0; cf < 4; ++cf) {
        aw[0][cf] = Wf[(size_t)(cf * 32 + 0) * 64];
        aw[1][cf] = Wf[(size_t)(cf * 32 + 1) * 64];
    }
    bw[0][0] = F0[0 * 64]; bw[0][1] = F1[0 * 64];
    bw[1][0] = F0[1 * 64]; bw[1][1] = F1[1 * 64];

    for (int kt = 0; kt < 32; kt += 2) {
        int kn = kt + 2;
        if (kn < 32) {
            #pragma unroll
            for (int cf = 0; cf < 4; ++cf) {
                an[0][cf] = Wf[(size_t)(cf * 32 + kn) * 64];
                an[1][cf] = Wf[(size_t)(cf * 32 + kn + 1) * 64];
            }
            bn[0][0] = F0[(size_t)kn * 64];       bn[0][1] = F1[(size_t)kn * 64];
            bn[1][0] = F0[(size_t)(kn + 1) * 64]; bn[1][1] = F1[(size_t)(kn + 1) * 64];
        }
        #pragma unroll
        for (int j = 0; j < 2; ++j)
            #pragma unroll
            for (int cf = 0; cf < 4; ++cf) {
                acc[cf][0] = __builtin_amdgcn_mfma_f32_16x16x32_bf16(aw[j][cf], bw[j][0], acc[cf][0], 0, 0, 0);
                acc[cf][1] = __builtin_amdgcn_mfma_f32_16x16x32_bf16(aw[j][cf], bw[j][1], acc[cf][1], 0, 0, 0);
            }
        #pragma unroll
        for (int j = 0; j < 2; ++j) {
            #pragma unroll
            for (int cf = 0; cf < 4; ++cf) aw[j][cf] = an[j][cf];
            bw[j][0] = bn[j][0]; bw[j][1] = bn[j][1];
        }
    }
    // D layout: ch = w*64 + cf*16 + q*4 + reg, node = m0 + g*16 + l15
    #pragma unroll
    for (int g = 0; g < 2; ++g) {
        int node = m0 + g * 16 + l15;
        if (node < N_NODES) {
            ushort* base = (w < 2) ? (Py + (size_t)node * FC + w * 64)
                                   : (Pz + (size_t)node * FC + (w - 2) * 64);
            #pragma unroll
            for (int cf = 0; cf < 4; ++cf) {
                f32x4 v = acc[cf][g];
                uint2 pk;
                pk.x = pkbf(v[0], v[1]);
                pk.y = pkbf(v[2], v[3]);
                *(uint2*)(base + cf * 16 + q * 4) = pk;
            }
        }
    }
}

// ---------------- fused gather + SAGE combine + MLP tail (unchanged) --------
__global__ __launch_bounds__(256) void fused_tail(const ushort* __restrict__ Py,
                                                  const ushort* __restrict__ Pz,
                                                  const int* __restrict__ deg,
                                                  const int* __restrict__ col,
                                                  const float* __restrict__ addf,
                                                  const float* __restrict__ bl,
                                                  const float* __restrict__ W1,
                                                  const float* __restrict__ b1,
                                                  const float* __restrict__ W2,
                                                  const float* __restrict__ b2,
                                                  const float* __restrict__ gamma,
                                                  const float* __restrict__ beta,
                                                  const float* __restrict__ rmean,
                                                  const float* __restrict__ rvar,
                                                  float* __restrict__ out) {
    __shared__ float W1s[XCH][MID + 3];
    __shared__ float xbuf[4][XCH + 4];
    __shared__ float hbuf[4][MID + 3];
    int t = threadIdx.x;
    for (int idx = t; idx < MID * XCH; idx += 256) {
        int j = idx / XCH, k = idx - j * XCH;
        W1s[k][j] = W1[idx];
    }
    __syncthreads();
    int w = t >> 6, lane = t & 63;
    int n = blockIdx.x * 4 + w;
    bool valid = (n < N_NODES);
    int d = valid ? deg[n] : 0;
    if (d > MAXDEG) d = MAXDEG;
    int g = lane >> 4, c16 = lane & 15;
    float s[8] = {0.f, 0.f, 0.f, 0.f, 0.f, 0.f, 0.f, 0.f};
    if (d > 0) {
        int cidx = col[n * MAXDEG + (lane < d ? lane : 0)];
        for (int i = 0; i < d; i += 16) {
            int e[4];
            uint4 v[4];
            #pragma unroll
            for (int j = 0; j < 4; ++j) {
                int ee = i + g + j * 4;
                e[j] = __shfl(cidx, (ee < d) ? ee : 0);
            }
            #pragma unroll
            for (int j = 0; j < 4; ++j)
                v[j] = *(const uint4*)&Py[(size_t)e[j] * FC + c16 * 8];
            #pragma unroll
            for (int j = 0; j < 4; ++j) {
                if (i + g + j * 4 < d) {
                    s[0] += bflo(v[j].x); s[1] += bfhi(v[j].x);
                    s[2] += bflo(v[j].y); s[3] += bfhi(v[j].y);
                    s[4] += bflo(v[j].z); s[5] += bfhi(v[j].z);
                    s[6] += bflo(v[j].w); s[7] += bfhi(v[j].w);
                }
            }
        }
        #pragma unroll
        for (int r = 0; r < 8; ++r) {
            s[r] += __shfl_xor(s[r], 16);
            s[r] += __shfl_xor(s[r], 32);
        }
    }
    if (valid) {
        if (lane < 16) {
            #pragma unroll
            for (int r = 0; r < 8; ++r) xbuf[w][lane * 8 + r] = s[r];
        }
        float invd = 1.0f / (float)(d > 1 ? d : 1);
        unsigned int vr = *(const unsigned int*)&Pz[(size_t)n * FC + lane * 2];
        float x0 = xbuf[w][2 * lane] * invd + bl[2 * lane] + bflo(vr);
        float x1 = xbuf[w][2 * lane + 1] * invd + bl[2 * lane + 1] + bfhi(vr);
        x0 = (x0 >= 0.f) ? x0 : 0.01f * x0;
        x1 = (x1 >= 0.f) ? x1 : 0.01f * x1;
        xbuf[w][2 * lane] = x0;
        xbuf[w][2 * lane + 1] = x1;
        if (lane < ADD_CH) xbuf[w][FC + lane] = addf[(size_t)n * ADD_CH + lane];
        if (lane < MID) {
            float h = b1[lane];
            #pragma unroll 4
            for (int k = 0; k < XCH; ++k) h += W1s[k][lane] * xbuf[w][k];
            h = fmaxf(h, 0.0f);
            h = gamma[lane] * (h - rmean[lane]) * rsqrtf(rvar[lane] + 1e-5f) + beta[lane];
            hbuf[w][lane] = h;
        }
        if (lane < OUT_CH) {
            float o = b2[lane];
            #pragma unroll
            for (int j = 0; j < MID; ++j) o += W2[lane * MID + j] * hbuf[w][j];
            out[(size_t)n * OUT_CH + lane] = o;
        }
    }
}

// ---------------- launch ----------------

extern "C" void kernel_launch(void* const* d_in, const int* in_sizes, int n_in,
                              void* d_out, int out_size, void* d_ws, size_t ws_size,
                              hipStream_t stream) {
    const float* features = (const float*)d_in[0];
    const int*   edges    = (const int*)d_in[1];
    const float* addf     = (const float*)d_in[4];
    const float* Wl       = (const float*)d_in[5];
    const float* bl       = (const float*)d_in[6];
    const float* Wr       = (const float*)d_in[7];
    const float* W1       = (const float*)d_in[8];
    const float* b1       = (const float*)d_in[9];
    const float* W2       = (const float*)d_in[10];
    const float* b2       = (const float*)d_in[11];
    const float* gamma    = (const float*)d_in[12];
    const float* beta     = (const float*)d_in[13];
    const float* rmean    = (const float*)d_in[14];
    const float* rvar     = (const float*)d_in[15];
    float* out = (float*)d_out;

    char* ws = (char*)d_ws;
    size_t off = 0;
    ushort* Py = (ushort*)(ws + off);     off += (size_t)N_NODES * FC * 2;        // 6.4 MB
    ushort* Pz = (ushort*)(ws + off);     off += (size_t)N_NODES * FC * 2;        // 6.4 MB
    ushort* Wpk = (ushort*)(ws + off);    off += (size_t)16 * 32 * 64 * 16;       // 512 KB
    int* cursor = (int*)(ws + off);       off += (size_t)N_NODES * 4;             // 100 KB
    int* col = (int*)(ws + off);          off += (size_t)N_NODES * MAXDEG * 4;    // 6.4 MB

    (void)hipMemsetAsync(cursor, 0, (size_t)N_NODES * 4, stream);

    prep_kernel<<<WSWZ_B + BUILD_B, 256, 0, stream>>>(Wl, Wr, edges, Wpk, cursor, col);

    gemm_kernel<<<(N_NODES + 31) / 32, 256, 0, stream>>>(features, Wpk, Py, Pz);

    fused_tail<<<(N_NODES + 3) / 4, 256, 0, stream>>>(Py, Pz, cursor, col, addf, bl,
                                                      W1, b1, W2, b2, gamma, beta,
                                                      rmean, rvar, out);
}

// Round 11
// 270.916 us; speedup vs baseline: 1.1042x; 1.0891x over previous
//
#include <hip/hip_runtime.h>

#define N_NODES 25000
#define N_EDGES 400000
#define IN_CH 1024
#define FC 128
#define ADD_CH 20
#define XCH 148   // FC + ADD
#define MID 37
#define OUT_CH 3
#define MAXDEG 64

typedef short bf16x8 __attribute__((ext_vector_type(8)));
typedef float f32x4 __attribute__((ext_vector_type(4)));

__device__ __forceinline__ unsigned int f2bf(float x) {
    unsigned int u = __builtin_bit_cast(unsigned int, x);
    unsigned int lsb = (u >> 16) & 1u;
    u += 0x7fffu + lsb;           // round-to-nearest-even
    return u >> 16;
}
__device__ __forceinline__ unsigned int pkbf(float a, float b) {
    return f2bf(a) | (f2bf(b) << 16);
}
__device__ __forceinline__ float bflo(unsigned int v) {
    return __builtin_bit_cast(float, v << 16);
}
__device__ __forceinline__ float bfhi(unsigned int v) {
    return __builtin_bit_cast(float, v & 0xffff0000u);
}

// ---------------- prep: W swizzle + cursor zero ----------------
// W frag layout: unit (chgrp, kt) = 64 lanes x 16 B contiguous; lane (q,l15)
// holds W[chgrp*16+l15][kt*32+q*8 .. +8] as bf16x8.
#define WSWZ_B 16
#define ZERO_B 98   // 98*256 >= 25000

__global__ __launch_bounds__(256) void prep_kernel(const float* __restrict__ Wl,
                                                   const float* __restrict__ Wr,
                                                   ushort* __restrict__ Wpk,
                                                   int* __restrict__ cursor) {
    int b = blockIdx.x, t = threadIdx.x;
    if (b < WSWZ_B) {
        int w = t >> 6, lane = t & 63, l15 = lane & 15, q8 = (lane >> 4) * 8;
        int ch = b * 16 + l15;
        const float* src = (ch < FC) ? (Wl + (size_t)ch * IN_CH)
                                     : (Wr + (size_t)(ch - FC) * IN_CH);
        #pragma unroll
        for (int j = 0; j < 8; ++j) {
            int kt = w * 8 + j;
            float4 lo = *(const float4*)(src + kt * 32 + q8);
            float4 hi = *(const float4*)(src + kt * 32 + q8 + 4);
            uint4 pk;
            pk.x = pkbf(lo.x, lo.y); pk.y = pkbf(lo.z, lo.w);
            pk.z = pkbf(hi.x, hi.y); pk.w = pkbf(hi.z, hi.w);
            ((uint4*)Wpk)[(size_t)(b * 32 + kt) * 64 + lane] = pk;
        }
    } else {
        int i = (b - WSWZ_B) * 256 + t;
        if (i < N_NODES) cursor[i] = 0;
    }
}

// ---------------- fused stage + GEMM + CSR build (hetero grid) --------------
// GEMM blocks: 512 thr = 8 waves, 32 nodes x 256 ch, 64 KB LDS F-frags.
//   Wave w = 32 ch (chgrps 2w,2w+1) x 32 nodes -> acc[2][2] = 16 VGPRs.
//   2 blocks/CU => 16 waves/CU = 4/SIMD (TLP was the round-10 limiter).
//   No inner barrier; depth-2 W (L2-hot) + F (LDS) pipelines.
// Build blocks: bucket CSR col[dst*64+pos] via atomics, overlaps on spare CUs.
#define GEMM_B 782    // ceil(25000/32)
#define BUILD_B 782   // ceil(400000/512)

__global__ __launch_bounds__(512, 4) void gemm_build(const float* __restrict__ A,
                                                     const ushort* __restrict__ Wpk,
                                                     ushort* __restrict__ Py,
                                                     ushort* __restrict__ Pz,
                                                     const int* __restrict__ edges,
                                                     int* __restrict__ cursor,
                                                     int* __restrict__ col) {
    __shared__ __align__(16) ushort Fs[2 * 32 * 64 * 8];   // 64 KB frag layout
    int b = blockIdx.x, t = threadIdx.x;
    if (b >= GEMM_B) {
        int e = (b - GEMM_B) * 512 + t;
        if (e < N_EDGES) {
            int dst = edges[N_EDGES + e];
            int pos = atomicAdd(&cursor[dst], 1);
            if (pos < MAXDEG) col[dst * MAXDEG + pos] = edges[e];
        }
        return;
    }
    int w = t >> 6, lane = t & 63;
    int l15 = lane & 15, q = lane >> 4;
    int m0 = b * 32;

    // ---- stage 32 feature rows -> LDS frags (XOR-swizzled) ----
    {
        int r = t >> 4;            // row-in-tile 0..31
        int p0 = t & 15;           // position 0..15
        int row = m0 + r; if (row >= N_NODES) row = N_NODES - 1;
        const float* src = A + (size_t)row * IN_CH;
        int g = r >> 4, l = r & 15;
        #pragma unroll
        for (int h = 0; h < 2; ++h) {
            float4 lo[4], hi[4];
            #pragma unroll
            for (int m = 0; m < 4; ++m) {
                int o = (h * 4 + m) * 16 + p0;
                lo[m] = *(const float4*)(src + o * 8);
                hi[m] = *(const float4*)(src + o * 8 + 4);
            }
            #pragma unroll
            for (int m = 0; m < 4; ++m) {
                int o = (h * 4 + m) * 16 + p0;
                int kt = o >> 2, qq = o & 3;
                uint4 pk;
                pk.x = pkbf(lo[m].x, lo[m].y); pk.y = pkbf(lo[m].z, lo[m].w);
                pk.z = pkbf(hi[m].x, hi[m].y); pk.w = pkbf(hi[m].z, hi[m].w);
                int u = (g * 32 + kt) * 64 + qq * 16 + ((l + qq) & 15);
                *(uint4*)&Fs[(size_t)u * 8] = pk;
            }
        }
    }
    __syncthreads();

    int ru = q * 16 + ((l15 + q) & 15);     // swizzled read unit within kt-block
    const bf16x8* F0 = (const bf16x8*)Fs + ru;
    const bf16x8* F1 = (const bf16x8*)Fs + 32 * 64 + ru;
    const bf16x8* W0 = (const bf16x8*)Wpk + (size_t)(w * 2 + 0) * 32 * 64 + lane;
    const bf16x8* W1 = (const bf16x8*)Wpk + (size_t)(w * 2 + 1) * 32 * 64 + lane;

    f32x4 acc[2][2] = {};
    bf16x8 aw[2][2], an[2][2], bw[2][2], bn[2][2];
    aw[0][0] = W0[0];  aw[0][1] = W1[0];
    aw[1][0] = W0[64]; aw[1][1] = W1[64];
    bw[0][0] = F0[0];  bw[0][1] = F1[0];
    bw[1][0] = F0[64]; bw[1][1] = F1[64];

    for (int kt = 0; kt < 32; kt += 2) {
        int kn = kt + 2;
        if (kn < 32) {
            an[0][0] = W0[(size_t)kn * 64];       an[0][1] = W1[(size_t)kn * 64];
            an[1][0] = W0[(size_t)(kn + 1) * 64]; an[1][1] = W1[(size_t)(kn + 1) * 64];
            bn[0][0] = F0[(size_t)kn * 64];       bn[0][1] = F1[(size_t)kn * 64];
            bn[1][0] = F0[(size_t)(kn + 1) * 64]; bn[1][1] = F1[(size_t)(kn + 1) * 64];
        }
        #pragma unroll
        for (int j = 0; j < 2; ++j)
            #pragma unroll
            for (int cf = 0; cf < 2; ++cf) {
                acc[cf][0] = __builtin_amdgcn_mfma_f32_16x16x32_bf16(aw[j][cf], bw[j][0], acc[cf][0], 0, 0, 0);
                acc[cf][1] = __builtin_amdgcn_mfma_f32_16x16x32_bf16(aw[j][cf], bw[j][1], acc[cf][1], 0, 0, 0);
            }
        #pragma unroll
        for (int j = 0; j < 2; ++j)
            #pragma unroll
            for (int cf = 0; cf < 2; ++cf) {
                aw[j][cf] = an[j][cf];
                bw[j][cf] = bn[j][cf];
            }
    }
    // D layout: ch = w*32 + cf*16 + q*4 + reg, node = m0 + g*16 + l15
    #pragma unroll
    for (int g = 0; g < 2; ++g) {
        int node = m0 + g * 16 + l15;
        if (node < N_NODES) {
            ushort* base = (w < 4) ? (Py + (size_t)node * FC + w * 32)
                                   : (Pz + (size_t)node * FC + (w - 4) * 32);
            #pragma unroll
            for (int cf = 0; cf < 2; ++cf) {
                f32x4 v = acc[cf][g];
                uint2 pk;
                pk.x = pkbf(v[0], v[1]);
                pk.y = pkbf(v[2], v[3]);
                *(uint2*)(base + cf * 16 + q * 4) = pk;
            }
        }
    }
}

// ---------------- fused gather + SAGE combine + MLP tail (unchanged) --------
__global__ __launch_bounds__(256) void fused_tail(const ushort* __restrict__ Py,
                                                  const ushort* __restrict__ Pz,
                                                  const int* __restrict__ deg,
                                                  const int* __restrict__ col,
                                                  const float* __restrict__ addf,
                                                  const float* __restrict__ bl,
                                                  const float* __restrict__ W1,
                                                  const float* __restrict__ b1,
                                                  const float* __restrict__ W2,
                                                  const float* __restrict__ b2,
                                                  const float* __restrict__ gamma,
                                                  const float* __restrict__ beta,
                                                  const float* __restrict__ rmean,
                                                  const float* __restrict__ rvar,
                                                  float* __restrict__ out) {
    __shared__ float W1s[XCH][MID + 3];
    __shared__ float xbuf[4][XCH + 4];
    __shared__ float hbuf[4][MID + 3];
    int t = threadIdx.x;
    for (int idx = t; idx < MID * XCH; idx += 256) {
        int j = idx / XCH, k = idx - j * XCH;
        W1s[k][j] = W1[idx];
    }
    __syncthreads();
    int w = t >> 6, lane = t & 63;
    int n = blockIdx.x * 4 + w;
    bool valid = (n < N_NODES);
    int d = valid ? deg[n] : 0;
    if (d > MAXDEG) d = MAXDEG;
    int g = lane >> 4, c16 = lane & 15;
    float s[8] = {0.f, 0.f, 0.f, 0.f, 0.f, 0.f, 0.f, 0.f};
    if (d > 0) {
        int cidx = col[n * MAXDEG + (lane < d ? lane : 0)];
        for (int i = 0; i < d; i += 16) {
            int e[4];
            uint4 v[4];
            #pragma unroll
            for (int j = 0; j < 4; ++j) {
                int ee = i + g + j * 4;
                e[j] = __shfl(cidx, (ee < d) ? ee : 0);
            }
            #pragma unroll
            for (int j = 0; j < 4; ++j)
                v[j] = *(const uint4*)&Py[(size_t)e[j] * FC + c16 * 8];
            #pragma unroll
            for (int j = 0; j < 4; ++j) {
                if (i + g + j * 4 < d) {
                    s[0] += bflo(v[j].x); s[1] += bfhi(v[j].x);
                    s[2] += bflo(v[j].y); s[3] += bfhi(v[j].y);
                    s[4] += bflo(v[j].z); s[5] += bfhi(v[j].z);
                    s[6] += bflo(v[j].w); s[7] += bfhi(v[j].w);
                }
            }
        }
        #pragma unroll
        for (int r = 0; r < 8; ++r) {
            s[r] += __shfl_xor(s[r], 16);
            s[r] += __shfl_xor(s[r], 32);
        }
    }
    if (valid) {
        if (lane < 16) {
            #pragma unroll
            for (int r = 0; r < 8; ++r) xbuf[w][lane * 8 + r] = s[r];
        }
        float invd = 1.0f / (float)(d > 1 ? d : 1);
        unsigned int vr = *(const unsigned int*)&Pz[(size_t)n * FC + lane * 2];
        float x0 = xbuf[w][2 * lane] * invd + bl[2 * lane] + bflo(vr);
        float x1 = xbuf[w][2 * lane + 1] * invd + bl[2 * lane + 1] + bfhi(vr);
        x0 = (x0 >= 0.f) ? x0 : 0.01f * x0;
        x1 = (x1 >= 0.f) ? x1 : 0.01f * x1;
        xbuf[w][2 * lane] = x0;
        xbuf[w][2 * lane + 1] = x1;
        if (lane < ADD_CH) xbuf[w][FC + lane] = addf[(size_t)n * ADD_CH + lane];
        if (lane < MID) {
            float h = b1[lane];
            #pragma unroll 4
            for (int k = 0; k < XCH; ++k) h += W1s[k][lane] * xbuf[w][k];
            h = fmaxf(h, 0.0f);
            h = gamma[lane] * (h - rmean[lane]) * rsqrtf(rvar[lane] + 1e-5f) + beta[lane];
            hbuf[w][lane] = h;
        }
        if (lane < OUT_CH) {
            float o = b2[lane];
            #pragma unroll
            for (int j = 0; j < MID; ++j) o += W2[lane * MID + j] * hbuf[w][j];
            out[(size_t)n * OUT_CH + lane] = o;
        }
    }
}

// ---------------- launch ----------------

extern "C" void kernel_launch(void* const* d_in, const int* in_sizes, int n_in,
                              void* d_out, int out_size, void* d_ws, size_t ws_size,
                              hipStream_t stream) {
    const float* features = (const float*)d_in[0];
    const int*   edges    = (const int*)d_in[1];
    const float* addf     = (const float*)d_in[4];
    const float* Wl       = (const float*)d_in[5];
    const float* bl       = (const float*)d_in[6];
    const float* Wr       = (const float*)d_in[7];
    const float* W1       = (const float*)d_in[8];
    const float* b1       = (const float*)d_in[9];
    const float* W2       = (const float*)d_in[10];
    const float* b2       = (const float*)d_in[11];
    const float* gamma    = (const float*)d_in[12];
    const float* beta     = (const float*)d_in[13];
    const float* rmean    = (const float*)d_in[14];
    const float* rvar     = (const float*)d_in[15];
    float* out = (float*)d_out;

    char* ws = (char*)d_ws;
    size_t off = 0;
    ushort* Py = (ushort*)(ws + off);     off += (size_t)N_NODES * FC * 2;        // 6.4 MB
    ushort* Pz = (ushort*)(ws + off);     off += (size_t)N_NODES * FC * 2;        // 6.4 MB
    ushort* Wpk = (ushort*)(ws + off);    off += (size_t)16 * 32 * 64 * 16;       // 512 KB
    int* cursor = (int*)(ws + off);       off += (size_t)N_NODES * 4;             // 100 KB
    int* col = (int*)(ws + off);          off += (size_t)N_NODES * MAXDEG * 4;    // 6.4 MB

    prep_kernel<<<WSWZ_B + ZERO_B, 256, 0, stream>>>(Wl, Wr, Wpk, cursor);

    gemm_build<<<GEMM_B + BUILD_B, 512, 0, stream>>>(features, Wpk, Py, Pz,
                                                     edges, cursor, col);

    fused_tail<<<(N_NODES + 3) / 4, 256, 0, stream>>>(Py, Pz, cursor, col, addf, bl,
                                                      W1, b1, W2, b2, gamma, beta,
                                                      rmean, rvar, out);
}